// Round 4
// baseline (713.160 us; speedup 1.0000x reference)
//
#include <hip/hip_runtime.h>

// y[b, i] = sum v * x[b, j] + biases[i]
// 320k edges, each a dense 4x4 block at (4r, 4c); values row-major per edge.
// Round 4: L2-pinned gather. Batch windows of 32 lanes (per-window xh slice
// 2.6 MB < 4 MB XCD L2); window sweeps pinned to XCDs via blockIdx%8;
// nontemporal out stores; parallel 3-phase scan for the CSR build.

typedef _Float16 h2_t __attribute__((ext_vector_type(2)));
typedef float f4_t __attribute__((ext_vector_type(4)));

__device__ __forceinline__ h2_t as_h2(unsigned u) {
  union { unsigned u; h2_t h; } v; v.u = u; return v.h;
}

__device__ __forceinline__ float fdot2(h2_t a, h2_t b, float c) {
#if __has_builtin(__builtin_amdgcn_fdot2)
  return __builtin_amdgcn_fdot2(a, b, c, false);
#else
  return c + (float)a.x * (float)b.x + (float)a.y * (float)b.y;
#endif
}

__global__ void hist_kernel(const int* __restrict__ indices, int* __restrict__ cnt, int E) {
  int e = blockIdx.x * blockDim.x + threadIdx.x;
  if (e >= E) return;
  int bi = indices[(size_t)e * 32];
  atomicAdd(&cnt[bi >> 2], 1);
}

// ---- parallel scan over n counts: reduce -> wave-scan of partials -> final ----
__global__ void scan_reduce_kernel(const int* __restrict__ cnt, int* __restrict__ partial, int n) {
  __shared__ int sh[256];
  int i = blockIdx.x * 256 + threadIdx.x;
  sh[threadIdx.x] = (i < n) ? cnt[i] : 0;
  __syncthreads();
  for (int off = 128; off > 0; off >>= 1) {
    if (threadIdx.x < off) sh[threadIdx.x] += sh[threadIdx.x + off];
    __syncthreads();
  }
  if (threadIdx.x == 0) partial[blockIdx.x] = sh[0];
}

__global__ void scan_mid_kernel(const int* __restrict__ partial, int* __restrict__ offs, int nb) {
  // single wave inclusive scan of nb (<=64) partials -> exclusive offsets
  int t = threadIdx.x;
  int v = (t < nb) ? partial[t] : 0;
  for (int d = 1; d < 64; d <<= 1) {
    int u = __shfl_up(v, d);
    if (t >= d) v += u;
  }
  if (t < nb) offs[t] = v;  // inclusive; final kernel uses offs[blk-1]
}

__global__ void scan_final_kernel(const int* __restrict__ cnt, const int* __restrict__ offs,
                                  int* __restrict__ row_start, int n) {
  __shared__ int sh[256];
  int blk = blockIdx.x;
  int i = blk * 256 + threadIdx.x;
  int v = (i < n) ? cnt[i] : 0;
  sh[threadIdx.x] = v;
  __syncthreads();
  for (int off = 1; off < 256; off <<= 1) {
    int add = (threadIdx.x >= off) ? sh[threadIdx.x - off] : 0;
    __syncthreads();
    sh[threadIdx.x] += add;
    __syncthreads();
  }
  int base = (blk == 0) ? 0 : offs[blk - 1];
  if (i < n) row_start[i + 1] = sh[threadIdx.x] + base;
  if (blk == 0 && threadIdx.x == 0) row_start[0] = 0;
}

// fallback serial-ish scan for odd sizes
__global__ void scan_kernel(const int* __restrict__ cnt, int* __restrict__ row_start, int n) {
  __shared__ int buf[1024];
  __shared__ int carry_s;
  int t = threadIdx.x;
  if (t == 0) { carry_s = 0; row_start[0] = 0; }
  __syncthreads();
  for (int base = 0; base < n; base += 1024) {
    int v = (base + t < n) ? cnt[base + t] : 0;
    buf[t] = v;
    __syncthreads();
    for (int off = 1; off < 1024; off <<= 1) {
      int add = (t >= off) ? buf[t - off] : 0;
      __syncthreads();
      buf[t] += add;
      __syncthreads();
    }
    if (base + t < n) row_start[base + t + 1] = buf[t] + carry_s;
    __syncthreads();
    if (t == 0) carry_s += buf[1023];
    __syncthreads();
  }
}

__global__ void scatter_kernel(const int* __restrict__ indices, const int* __restrict__ row_start,
                               int* __restrict__ cursor, int2* __restrict__ edge_list, int E) {
  int e = blockIdx.x * blockDim.x + threadIdx.x;
  if (e >= E) return;
  int bi = indices[(size_t)e * 32];
  int bj = indices[(size_t)e * 32 + 1];
  int r = bi >> 2, c = bj >> 2;
  int pos = atomicAdd(&cursor[r], 1);
  edge_list[row_start[r] + pos] = make_int2(c, e);
}

// vals (fp32, edge-major 4x4 row-major) -> vals_h (fp16, CSR order)
__global__ void reorder_kernel(const int2* __restrict__ edge_list, const float* __restrict__ vals,
                               _Float16* __restrict__ vals_h, int* __restrict__ col_sorted, int E) {
  int tid = blockIdx.x * blockDim.x + threadIdx.x;
  int p = tid >> 4;
  int i = tid & 15;
  if (p >= E) return;
  int2 ce = edge_list[p];
  vals_h[(size_t)p * 16 + i] = (_Float16)vals[(size_t)ce.y * 16 + i];
  if (i == 0) col_sorted[p] = ce.x;
}

// x[b][4c+k] (fp32) -> xh[((c*batch)+b)*4 + k] (fp16 packed per node)
__global__ void pack_fp16_kernel(const float* __restrict__ in, uint2* __restrict__ out,
                                 int batch, int size) {
  __shared__ float tile[64][65];
  int c0 = blockIdx.x * 64;
  int b0 = blockIdx.y * 64;
  int tx = threadIdx.x & 63, ty = threadIdx.x >> 6;
#pragma unroll
  for (int k = 0; k < 64; k += 4) {
    int b = b0 + ty + k, c = c0 + tx;
    if (b < batch && c < size) tile[ty + k][tx] = in[(size_t)b * size + c];
  }
  __syncthreads();
#pragma unroll
  for (int it = 0; it < 4; ++it) {
    int idx = it * 256 + threadIdx.x;
    int cn_local = idx >> 6;
    int bl = idx & 63;
    int c_node = (c0 >> 2) + cn_local;
    int b = b0 + bl;
    if (b < batch && (c_node * 4 + 3) < size) {
      union { _Float16 h[4]; uint2 u; } cv;
      cv.h[0] = (_Float16)tile[bl][cn_local * 4 + 0];
      cv.h[1] = (_Float16)tile[bl][cn_local * 4 + 1];
      cv.h[2] = (_Float16)tile[bl][cn_local * 4 + 2];
      cv.h[3] = (_Float16)tile[bl][cn_local * 4 + 3];
      out[(size_t)c_node * batch + b] = cv.u;
    }
  }
}

__device__ __forceinline__ void edge_acc(const _Float16* __restrict__ vh, size_t p,
                                         uint2 xu, float* __restrict__ acc) {
  uint4 a = *(const uint4*)(vh + p * 16);
  uint4 c = *(const uint4*)(vh + p * 16 + 8);
  h2_t x01 = as_h2(xu.x), x23 = as_h2(xu.y);
  acc[0] = fdot2(as_h2(a.x), x01, acc[0]);
  acc[0] = fdot2(as_h2(a.y), x23, acc[0]);
  acc[1] = fdot2(as_h2(a.z), x01, acc[1]);
  acc[1] = fdot2(as_h2(a.w), x23, acc[1]);
  acc[2] = fdot2(as_h2(c.x), x01, acc[2]);
  acc[2] = fdot2(as_h2(c.y), x23, acc[2]);
  acc[3] = fdot2(as_h2(c.z), x01, acc[3]);
  acc[3] = fdot2(as_h2(c.w), x23, acc[3]);
}

// L2-pinned spmm: block = 8 quads x 32 batch lanes. id&7 selects XCD (empirical
// round-robin); XCD x sweeps windows x, x+8, ... so each window's 2.6 MB xh
// slice stays resident in that XCD's 4 MB L2 for the whole sweep.
__global__ __launch_bounds__(256) void spmm_kernel(
    const int* __restrict__ row_start, const int* __restrict__ col_sorted,
    const _Float16* __restrict__ vals_h, const uint2* __restrict__ xh,
    const float* __restrict__ biases, float* __restrict__ out,
    int n_nodes, int batch, int size, int nqp) {
  int id = blockIdx.x;
  int xcd = id & 7;
  int j = id >> 3;
  int wg = j / nqp;
  int qp = j - wg * nqp;
  int window = xcd + 8 * wg;
  int t = threadIdx.x;
  int ql = t >> 5;
  int bl = t & 31;
  int quad = qp * 8 + ql;
  int b = window * 32 + bl;
  if (quad * 4 >= n_nodes || b >= batch) return;

  float acc[4][4];
#pragma unroll
  for (int i = 0; i < 16; ++i) ((float*)acc)[i] = 0.f;

#pragma unroll
  for (int rr = 0; rr < 4; ++rr) {
    int r = quad * 4 + rr;
    if (r >= n_nodes) break;
    int s = row_start[r];
    int e = row_start[r + 1];
    int p = s;
    for (; p + 3 < e; p += 4) {
      int c0 = col_sorted[p];
      int c1 = col_sorted[p + 1];
      int c2 = col_sorted[p + 2];
      int c3 = col_sorted[p + 3];
      uint2 x0 = xh[(size_t)c0 * batch + b];
      uint2 x1 = xh[(size_t)c1 * batch + b];
      uint2 x2 = xh[(size_t)c2 * batch + b];
      uint2 x3 = xh[(size_t)c3 * batch + b];
      edge_acc(vals_h, (size_t)p,     x0, acc[rr]);
      edge_acc(vals_h, (size_t)p + 1, x1, acc[rr]);
      edge_acc(vals_h, (size_t)p + 2, x2, acc[rr]);
      edge_acc(vals_h, (size_t)p + 3, x3, acc[rr]);
    }
    for (; p < e; ++p) {
      int c = col_sorted[p];
      uint2 xu = xh[(size_t)c * batch + b];
      edge_acc(vals_h, (size_t)p, xu, acc[rr]);
    }
  }

#pragma unroll
  for (int rr = 0; rr < 4; ++rr) {
    int r = quad * 4 + rr;
    if (r >= n_nodes) break;
    float4 bias = *(const float4*)&biases[r << 2];
    f4_t o;
    o[0] = acc[rr][0] + bias.x;
    o[1] = acc[rr][1] + bias.y;
    o[2] = acc[rr][2] + bias.z;
    o[3] = acc[rr][3] + bias.w;
    __builtin_nontemporal_store(o, (f4_t*)&out[(size_t)b * size + (r << 2)]);
  }
}

// Fallback when ws can't hold xh: gather fp32 x directly, fp16 V.
__global__ __launch_bounds__(256) void spmm_fb_kernel(
    const int* __restrict__ row_start, const int* __restrict__ col_sorted,
    const _Float16* __restrict__ vals_h, const float* __restrict__ x,
    const float* __restrict__ biases, float* __restrict__ out,
    int n_nodes, int batch, int size) {
  int quad = blockIdx.x;
  int b = blockIdx.y * blockDim.x + threadIdx.x;
  if (b >= batch || quad * 4 >= n_nodes) return;
  float acc[4][4];
#pragma unroll
  for (int i = 0; i < 16; ++i) ((float*)acc)[i] = 0.f;
#pragma unroll
  for (int rr = 0; rr < 4; ++rr) {
    int r = quad * 4 + rr;
    if (r >= n_nodes) break;
    int s = row_start[r], e = row_start[r + 1];
    for (int p = s; p < e; ++p) {
      int c = col_sorted[p];
      float4 xv = *(const float4*)&x[(size_t)b * size + (c << 2)];
      const _Float16* V = vals_h + (size_t)p * 16;
#pragma unroll
      for (int i = 0; i < 4; ++i) {
        acc[rr][i] += (float)V[i * 4 + 0] * xv.x + (float)V[i * 4 + 1] * xv.y +
                      (float)V[i * 4 + 2] * xv.z + (float)V[i * 4 + 3] * xv.w;
      }
    }
  }
#pragma unroll
  for (int rr = 0; rr < 4; ++rr) {
    int r = quad * 4 + rr;
    if (r >= n_nodes) break;
    float4 bias = *(const float4*)&biases[r << 2];
    float4 o = make_float4(acc[rr][0] + bias.x, acc[rr][1] + bias.y,
                           acc[rr][2] + bias.z, acc[rr][3] + bias.w);
    *(float4*)&out[(size_t)b * size + (r << 2)] = o;
  }
}

// Last-resort fallback (tiny ws)
__global__ void bias_init_kernel(float* __restrict__ out, const float* __restrict__ biases,
                                 int batch, int size) {
  size_t t = (size_t)blockIdx.x * blockDim.x + threadIdx.x;
  size_t total = (size_t)batch * size;
  if (t >= total) return;
  out[t] = biases[t % size];
}

__global__ void atomic_spmm_kernel(const int* __restrict__ indices, const float* __restrict__ vals,
                                   const float* __restrict__ x, float* __restrict__ out,
                                   int nnz, int batch, int size) {
  int n = blockIdx.x;
  if (n >= nnz) return;
  int i = indices[(size_t)n * 2];
  int j = indices[(size_t)n * 2 + 1];
  float v = vals[n];
  for (int b = threadIdx.x; b < batch; b += blockDim.x) {
    atomicAdd(&out[(size_t)b * size + i], v * x[(size_t)b * size + j]);
  }
}

extern "C" void kernel_launch(void* const* d_in, const int* in_sizes, int n_in,
                              void* d_out, int out_size, void* d_ws, size_t ws_size,
                              hipStream_t stream) {
  const float* x       = (const float*)d_in[0];
  const float* values  = (const float*)d_in[1];
  const float* biases  = (const float*)d_in[2];
  const int*   indices = (const int*)d_in[3];
  float* out = (float*)d_out;

  const int size    = in_sizes[2];        // 40000
  const int nnz     = in_sizes[1];        // 5,120,000
  const int batch   = in_sizes[0] / size; // 1024
  const int E       = nnz / 16;           // 320,000
  const int n_nodes = size / 4;           // 10,000

  // ---- workspace layout ----
  char* ws = (char*)d_ws;
  size_t off = 0;
  int* cnt = (int*)(ws + off);        off += (size_t)n_nodes * 4;
  int* cursor = (int*)(ws + off);     off += (size_t)n_nodes * 4;
  int* row_start = (int*)(ws + off);  off += ((size_t)n_nodes + 1) * 4;
  off = (off + 255) & ~(size_t)255;
  int* partial = (int*)(ws + off);    off += 64 * 4;
  int* offs = (int*)(ws + off);       off += 64 * 4;
  off = (off + 255) & ~(size_t)255;
  int* col_sorted = (int*)(ws + off); off += (size_t)E * 4;
  off = (off + 255) & ~(size_t)255;
  int2* edge_list = (int2*)(ws + off); off += (size_t)E * 8;
  off = (off + 255) & ~(size_t)255;
  _Float16* vals_h = (_Float16*)(ws + off); off += (size_t)E * 32;
  off = (off + 255) & ~(size_t)255;
  size_t need_csr = off;
  uint2* xh = (uint2*)(ws + off);
  off += (size_t)(size / 4) * batch * 8;
  size_t need_full = off;

  const int n_quads = (n_nodes + 3) / 4;

  if (ws_size >= need_csr) {
    hipMemsetAsync(cnt, 0, (size_t)2 * n_nodes * 4, stream);
    hist_kernel<<<(E + 255) / 256, 256, 0, stream>>>(indices, cnt, E);

    int nb = (n_nodes + 255) / 256;
    if (nb <= 64) {
      scan_reduce_kernel<<<nb, 256, 0, stream>>>(cnt, partial, n_nodes);
      scan_mid_kernel<<<1, 64, 0, stream>>>(partial, offs, nb);
      scan_final_kernel<<<nb, 256, 0, stream>>>(cnt, offs, row_start, n_nodes);
    } else {
      scan_kernel<<<1, 1024, 0, stream>>>(cnt, row_start, n_nodes);
    }

    scatter_kernel<<<(E + 255) / 256, 256, 0, stream>>>(indices, row_start, cursor, edge_list, E);
    reorder_kernel<<<((size_t)E * 16 + 255) / 256, 256, 0, stream>>>(edge_list, values, vals_h, col_sorted, E);

    if (ws_size >= need_full) {
      pack_fp16_kernel<<<dim3((size + 63) / 64, (batch + 63) / 64), 256, 0, stream>>>(
          x, xh, batch, size);
      int nqp = (n_quads + 7) / 8;                 // quad-pairs of 8 quads
      int nwin = (batch + 31) / 32;                // 32-lane batch windows
      int wgrp = (nwin + 7) / 8;                   // window groups of 8
      int grid = 8 * wgrp * nqp;
      spmm_kernel<<<grid, 256, 0, stream>>>(row_start, col_sorted, vals_h, xh,
                                            biases, out, n_nodes, batch, size, nqp);
    } else {
      dim3 grid(n_quads, (batch + 255) / 256);
      spmm_fb_kernel<<<grid, 256, 0, stream>>>(row_start, col_sorted, vals_h, x,
                                               biases, out, n_nodes, batch, size);
    }
  } else {
    size_t total = (size_t)batch * size;
    bias_init_kernel<<<(total + 255) / 256, 256, 0, stream>>>(out, biases, batch, size);
    atomic_spmm_kernel<<<nnz, 256, 0, stream>>>(indices, values, x, out, nnz, batch, size);
  }
}

// Round 5
// 494.998 us; speedup vs baseline: 1.4407x; 1.4407x over previous
//
#include <hip/hip_runtime.h>

// y[b, i] = sum v * x[b, j] + biases[i]
// 320k edges, each a dense 4x4 block at (4r, 4c); values row-major per edge.
// Round 5: revert to round-3 block shape (2 quads x 128 lanes, wave-uniform
// quad, readfirstlane row bounds, L2-merged stores). New: window-major grid
// ordering (all blocks of a batch window dispatch together -> live gather
// footprint ~10-20 MB, L3-resident) + 8-edge unroll for MLP.

typedef _Float16 h2_t __attribute__((ext_vector_type(2)));

__device__ __forceinline__ h2_t as_h2(unsigned u) {
  union { unsigned u; h2_t h; } v; v.u = u; return v.h;
}

__device__ __forceinline__ float fdot2(h2_t a, h2_t b, float c) {
#if __has_builtin(__builtin_amdgcn_fdot2)
  return __builtin_amdgcn_fdot2(a, b, c, false);
#else
  return c + (float)a.x * (float)b.x + (float)a.y * (float)b.y;
#endif
}

__global__ void hist_kernel(const int* __restrict__ indices, int* __restrict__ cnt, int E) {
  int e = blockIdx.x * blockDim.x + threadIdx.x;
  if (e >= E) return;
  int bi = indices[(size_t)e * 32];
  atomicAdd(&cnt[bi >> 2], 1);
}

// ---- parallel scan: reduce -> wave-scan of partials -> final ----
__global__ void scan_reduce_kernel(const int* __restrict__ cnt, int* __restrict__ partial, int n) {
  __shared__ int sh[256];
  int i = blockIdx.x * 256 + threadIdx.x;
  sh[threadIdx.x] = (i < n) ? cnt[i] : 0;
  __syncthreads();
  for (int off = 128; off > 0; off >>= 1) {
    if (threadIdx.x < off) sh[threadIdx.x] += sh[threadIdx.x + off];
    __syncthreads();
  }
  if (threadIdx.x == 0) partial[blockIdx.x] = sh[0];
}

__global__ void scan_mid_kernel(const int* __restrict__ partial, int* __restrict__ offs, int nb) {
  int t = threadIdx.x;
  int v = (t < nb) ? partial[t] : 0;
  for (int d = 1; d < 64; d <<= 1) {
    int u = __shfl_up(v, d);
    if (t >= d) v += u;
  }
  if (t < nb) offs[t] = v;  // inclusive
}

__global__ void scan_final_kernel(const int* __restrict__ cnt, const int* __restrict__ offs,
                                  int* __restrict__ row_start, int n) {
  __shared__ int sh[256];
  int blk = blockIdx.x;
  int i = blk * 256 + threadIdx.x;
  int v = (i < n) ? cnt[i] : 0;
  sh[threadIdx.x] = v;
  __syncthreads();
  for (int off = 1; off < 256; off <<= 1) {
    int add = (threadIdx.x >= off) ? sh[threadIdx.x - off] : 0;
    __syncthreads();
    sh[threadIdx.x] += add;
    __syncthreads();
  }
  int base = (blk == 0) ? 0 : offs[blk - 1];
  if (i < n) row_start[i + 1] = sh[threadIdx.x] + base;
  if (blk == 0 && threadIdx.x == 0) row_start[0] = 0;
}

__global__ void scan_kernel(const int* __restrict__ cnt, int* __restrict__ row_start, int n) {
  __shared__ int buf[1024];
  __shared__ int carry_s;
  int t = threadIdx.x;
  if (t == 0) { carry_s = 0; row_start[0] = 0; }
  __syncthreads();
  for (int base = 0; base < n; base += 1024) {
    int v = (base + t < n) ? cnt[base + t] : 0;
    buf[t] = v;
    __syncthreads();
    for (int off = 1; off < 1024; off <<= 1) {
      int add = (t >= off) ? buf[t - off] : 0;
      __syncthreads();
      buf[t] += add;
      __syncthreads();
    }
    if (base + t < n) row_start[base + t + 1] = buf[t] + carry_s;
    __syncthreads();
    if (t == 0) carry_s += buf[1023];
    __syncthreads();
  }
}

__global__ void scatter_kernel(const int* __restrict__ indices, const int* __restrict__ row_start,
                               int* __restrict__ cursor, int2* __restrict__ edge_list, int E) {
  int e = blockIdx.x * blockDim.x + threadIdx.x;
  if (e >= E) return;
  int bi = indices[(size_t)e * 32];
  int bj = indices[(size_t)e * 32 + 1];
  int r = bi >> 2, c = bj >> 2;
  int pos = atomicAdd(&cursor[r], 1);
  edge_list[row_start[r] + pos] = make_int2(c, e);
}

__global__ void reorder_kernel(const int2* __restrict__ edge_list, const float* __restrict__ vals,
                               _Float16* __restrict__ vals_h, int* __restrict__ col_sorted, int E) {
  int tid = blockIdx.x * blockDim.x + threadIdx.x;
  int p = tid >> 4;
  int i = tid & 15;
  if (p >= E) return;
  int2 ce = edge_list[p];
  vals_h[(size_t)p * 16 + i] = (_Float16)vals[(size_t)ce.y * 16 + i];
  if (i == 0) col_sorted[p] = ce.x;
}

// x[b][4c+k] (fp32) -> xh[((c*batch)+b)*4 + k] (fp16 packed per node)
__global__ void pack_fp16_kernel(const float* __restrict__ in, uint2* __restrict__ out,
                                 int batch, int size) {
  __shared__ float tile[64][65];
  int c0 = blockIdx.x * 64;
  int b0 = blockIdx.y * 64;
  int tx = threadIdx.x & 63, ty = threadIdx.x >> 6;
#pragma unroll
  for (int k = 0; k < 64; k += 4) {
    int b = b0 + ty + k, c = c0 + tx;
    if (b < batch && c < size) tile[ty + k][tx] = in[(size_t)b * size + c];
  }
  __syncthreads();
#pragma unroll
  for (int it = 0; it < 4; ++it) {
    int idx = it * 256 + threadIdx.x;
    int cn_local = idx >> 6;
    int bl = idx & 63;
    int c_node = (c0 >> 2) + cn_local;
    int b = b0 + bl;
    if (b < batch && (c_node * 4 + 3) < size) {
      union { _Float16 h[4]; uint2 u; } cv;
      cv.h[0] = (_Float16)tile[bl][cn_local * 4 + 0];
      cv.h[1] = (_Float16)tile[bl][cn_local * 4 + 1];
      cv.h[2] = (_Float16)tile[bl][cn_local * 4 + 2];
      cv.h[3] = (_Float16)tile[bl][cn_local * 4 + 3];
      out[(size_t)c_node * batch + b] = cv.u;
    }
  }
}

__device__ __forceinline__ void edge_acc(const _Float16* __restrict__ vh, size_t p,
                                         uint2 xu, float* __restrict__ acc) {
  uint4 a = *(const uint4*)(vh + p * 16);
  uint4 c = *(const uint4*)(vh + p * 16 + 8);
  h2_t x01 = as_h2(xu.x), x23 = as_h2(xu.y);
  acc[0] = fdot2(as_h2(a.x), x01, acc[0]);
  acc[0] = fdot2(as_h2(a.y), x23, acc[0]);
  acc[1] = fdot2(as_h2(a.z), x01, acc[1]);
  acc[1] = fdot2(as_h2(a.w), x23, acc[1]);
  acc[2] = fdot2(as_h2(c.x), x01, acc[2]);
  acc[2] = fdot2(as_h2(c.y), x23, acc[2]);
  acc[3] = fdot2(as_h2(c.z), x01, acc[3]);
  acc[3] = fdot2(as_h2(c.w), x23, acc[3]);
}

// Window-major spmm: grid.x = nwin * npairs; blocks of window w all dispatch
// before window w+1 -> live gather footprint = 1-2 window slices (~10-20 MB),
// L3-resident. Block = 2 quads x 128 batch lanes (wave-uniform quad).
__global__ __launch_bounds__(256) void spmm_kernel(
    const int* __restrict__ row_start, const int* __restrict__ col_sorted,
    const _Float16* __restrict__ vals_h, const uint2* __restrict__ xh,
    const float* __restrict__ biases, float* __restrict__ out,
    int n_nodes, int batch, int size, int npairs) {
  int bx = blockIdx.x;
  int w = bx / npairs;
  int qp = bx - w * npairs;
  int t = threadIdx.x;
  int quad = qp * 2 + (t >> 7);
  int b = w * 128 + (t & 127);
  if (quad * 4 >= n_nodes || b >= batch) return;

  const uint2* __restrict__ xb = xh + b;

  float acc[4][4];
#pragma unroll
  for (int i = 0; i < 16; ++i) ((float*)acc)[i] = 0.f;

#pragma unroll
  for (int rr = 0; rr < 4; ++rr) {
    int r = quad * 4 + rr;
    if (r >= n_nodes) break;
    int s = __builtin_amdgcn_readfirstlane(row_start[r]);
    int e = __builtin_amdgcn_readfirstlane(row_start[r + 1]);
    int p = s;
    for (; p + 7 < e; p += 8) {
      int c0 = col_sorted[p];
      int c1 = col_sorted[p + 1];
      int c2 = col_sorted[p + 2];
      int c3 = col_sorted[p + 3];
      int c4 = col_sorted[p + 4];
      int c5 = col_sorted[p + 5];
      int c6 = col_sorted[p + 6];
      int c7 = col_sorted[p + 7];
      uint2 x0 = xb[(size_t)c0 * batch];
      uint2 x1 = xb[(size_t)c1 * batch];
      uint2 x2 = xb[(size_t)c2 * batch];
      uint2 x3 = xb[(size_t)c3 * batch];
      uint2 x4 = xb[(size_t)c4 * batch];
      uint2 x5 = xb[(size_t)c5 * batch];
      uint2 x6 = xb[(size_t)c6 * batch];
      uint2 x7 = xb[(size_t)c7 * batch];
      edge_acc(vals_h, (size_t)p,     x0, acc[rr]);
      edge_acc(vals_h, (size_t)p + 1, x1, acc[rr]);
      edge_acc(vals_h, (size_t)p + 2, x2, acc[rr]);
      edge_acc(vals_h, (size_t)p + 3, x3, acc[rr]);
      edge_acc(vals_h, (size_t)p + 4, x4, acc[rr]);
      edge_acc(vals_h, (size_t)p + 5, x5, acc[rr]);
      edge_acc(vals_h, (size_t)p + 6, x6, acc[rr]);
      edge_acc(vals_h, (size_t)p + 7, x7, acc[rr]);
    }
    for (; p + 3 < e; p += 4) {
      int c0 = col_sorted[p];
      int c1 = col_sorted[p + 1];
      int c2 = col_sorted[p + 2];
      int c3 = col_sorted[p + 3];
      uint2 x0 = xb[(size_t)c0 * batch];
      uint2 x1 = xb[(size_t)c1 * batch];
      uint2 x2 = xb[(size_t)c2 * batch];
      uint2 x3 = xb[(size_t)c3 * batch];
      edge_acc(vals_h, (size_t)p,     x0, acc[rr]);
      edge_acc(vals_h, (size_t)p + 1, x1, acc[rr]);
      edge_acc(vals_h, (size_t)p + 2, x2, acc[rr]);
      edge_acc(vals_h, (size_t)p + 3, x3, acc[rr]);
    }
    for (; p < e; ++p) {
      int c = col_sorted[p];
      uint2 xu = xb[(size_t)c * batch];
      edge_acc(vals_h, (size_t)p, xu, acc[rr]);
    }
  }

#pragma unroll
  for (int rr = 0; rr < 4; ++rr) {
    int r = quad * 4 + rr;
    if (r >= n_nodes) break;
    float4 bias = *(const float4*)&biases[r << 2];
    float4 o = make_float4(acc[rr][0] + bias.x, acc[rr][1] + bias.y,
                           acc[rr][2] + bias.z, acc[rr][3] + bias.w);
    *(float4*)&out[(size_t)b * size + (r << 2)] = o;
  }
}

// Fallback when ws can't hold xh: gather fp32 x directly, fp16 V.
__global__ __launch_bounds__(256) void spmm_fb_kernel(
    const int* __restrict__ row_start, const int* __restrict__ col_sorted,
    const _Float16* __restrict__ vals_h, const float* __restrict__ x,
    const float* __restrict__ biases, float* __restrict__ out,
    int n_nodes, int batch, int size) {
  int quad = blockIdx.x;
  int b = blockIdx.y * blockDim.x + threadIdx.x;
  if (b >= batch || quad * 4 >= n_nodes) return;
  float acc[4][4];
#pragma unroll
  for (int i = 0; i < 16; ++i) ((float*)acc)[i] = 0.f;
#pragma unroll
  for (int rr = 0; rr < 4; ++rr) {
    int r = quad * 4 + rr;
    if (r >= n_nodes) break;
    int s = row_start[r], e = row_start[r + 1];
    for (int p = s; p < e; ++p) {
      int c = col_sorted[p];
      float4 xv = *(const float4*)&x[(size_t)b * size + (c << 2)];
      const _Float16* V = vals_h + (size_t)p * 16;
#pragma unroll
      for (int i = 0; i < 4; ++i) {
        acc[rr][i] += (float)V[i * 4 + 0] * xv.x + (float)V[i * 4 + 1] * xv.y +
                      (float)V[i * 4 + 2] * xv.z + (float)V[i * 4 + 3] * xv.w;
      }
    }
  }
#pragma unroll
  for (int rr = 0; rr < 4; ++rr) {
    int r = quad * 4 + rr;
    if (r >= n_nodes) break;
    float4 bias = *(const float4*)&biases[r << 2];
    float4 o = make_float4(acc[rr][0] + bias.x, acc[rr][1] + bias.y,
                           acc[rr][2] + bias.z, acc[rr][3] + bias.w);
    *(float4*)&out[(size_t)b * size + (r << 2)] = o;
  }
}

// Last-resort fallback (tiny ws)
__global__ void bias_init_kernel(float* __restrict__ out, const float* __restrict__ biases,
                                 int batch, int size) {
  size_t t = (size_t)blockIdx.x * blockDim.x + threadIdx.x;
  size_t total = (size_t)batch * size;
  if (t >= total) return;
  out[t] = biases[t % size];
}

__global__ void atomic_spmm_kernel(const int* __restrict__ indices, const float* __restrict__ vals,
                                   const float* __restrict__ x, float* __restrict__ out,
                                   int nnz, int batch, int size) {
  int n = blockIdx.x;
  if (n >= nnz) return;
  int i = indices[(size_t)n * 2];
  int j = indices[(size_t)n * 2 + 1];
  float v = vals[n];
  for (int b = threadIdx.x; b < batch; b += blockDim.x) {
    atomicAdd(&out[(size_t)b * size + i], v * x[(size_t)b * size + j]);
  }
}

extern "C" void kernel_launch(void* const* d_in, const int* in_sizes, int n_in,
                              void* d_out, int out_size, void* d_ws, size_t ws_size,
                              hipStream_t stream) {
  const float* x       = (const float*)d_in[0];
  const float* values  = (const float*)d_in[1];
  const float* biases  = (const float*)d_in[2];
  const int*   indices = (const int*)d_in[3];
  float* out = (float*)d_out;

  const int size    = in_sizes[2];        // 40000
  const int nnz     = in_sizes[1];        // 5,120,000
  const int batch   = in_sizes[0] / size; // 1024
  const int E       = nnz / 16;           // 320,000
  const int n_nodes = size / 4;           // 10,000

  // ---- workspace layout ----
  char* ws = (char*)d_ws;
  size_t off = 0;
  int* cnt = (int*)(ws + off);        off += (size_t)n_nodes * 4;
  int* cursor = (int*)(ws + off);     off += (size_t)n_nodes * 4;
  int* row_start = (int*)(ws + off);  off += ((size_t)n_nodes + 1) * 4;
  off = (off + 255) & ~(size_t)255;
  int* partial = (int*)(ws + off);    off += 64 * 4;
  int* offs = (int*)(ws + off);       off += 64 * 4;
  off = (off + 255) & ~(size_t)255;
  int* col_sorted = (int*)(ws + off); off += (size_t)E * 4;
  off = (off + 255) & ~(size_t)255;
  int2* edge_list = (int2*)(ws + off); off += (size_t)E * 8;
  off = (off + 255) & ~(size_t)255;
  _Float16* vals_h = (_Float16*)(ws + off); off += (size_t)E * 32;
  off = (off + 255) & ~(size_t)255;
  size_t need_csr = off;
  uint2* xh = (uint2*)(ws + off);
  off += (size_t)(size / 4) * batch * 8;
  size_t need_full = off;

  const int n_quads = (n_nodes + 3) / 4;

  if (ws_size >= need_csr) {
    hipMemsetAsync(cnt, 0, (size_t)2 * n_nodes * 4, stream);
    hist_kernel<<<(E + 255) / 256, 256, 0, stream>>>(indices, cnt, E);

    int nb = (n_nodes + 255) / 256;
    if (nb <= 64) {
      scan_reduce_kernel<<<nb, 256, 0, stream>>>(cnt, partial, n_nodes);
      scan_mid_kernel<<<1, 64, 0, stream>>>(partial, offs, nb);
      scan_final_kernel<<<nb, 256, 0, stream>>>(cnt, offs, row_start, n_nodes);
    } else {
      scan_kernel<<<1, 1024, 0, stream>>>(cnt, row_start, n_nodes);
    }

    scatter_kernel<<<(E + 255) / 256, 256, 0, stream>>>(indices, row_start, cursor, edge_list, E);
    reorder_kernel<<<((size_t)E * 16 + 255) / 256, 256, 0, stream>>>(edge_list, values, vals_h, col_sorted, E);

    if (ws_size >= need_full) {
      pack_fp16_kernel<<<dim3((size + 63) / 64, (batch + 63) / 64), 256, 0, stream>>>(
          x, xh, batch, size);
      int npairs = (n_quads + 1) / 2;
      int nwin = (batch + 127) / 128;
      spmm_kernel<<<nwin * npairs, 256, 0, stream>>>(row_start, col_sorted, vals_h, xh,
                                                     biases, out, n_nodes, batch, size, npairs);
    } else {
      dim3 grid(n_quads, (batch + 255) / 256);
      spmm_fb_kernel<<<grid, 256, 0, stream>>>(row_start, col_sorted, vals_h, x,
                                               biases, out, n_nodes, batch, size);
    }
  } else {
    size_t total = (size_t)batch * size;
    bias_init_kernel<<<(total + 255) / 256, 256, 0, stream>>>(out, biases, batch, size);
    atomic_spmm_kernel<<<nnz, 256, 0, stream>>>(indices, values, x, out, nnz, batch, size);
  }
}